// Round 14
// baseline (275.242 us; speedup 1.0000x reference)
//
#include <hip/hip_runtime.h>
#include <hip/hip_bf16.h>
#include <cstdint>
#include <cstddef>

// ---------------------------------------------------------------------------
// FarmerGAT round 14: r10 structure restored (best measured: 258us), ONE
// change: agg1 unroll 4->8 (16 rows in flight per wave).
//   memset(deg) -> kA [hist(saves ordinal) | prep w1t/w2t] -> scan_blocks
//   (-> rloc,bsum) -> kB [gemm1 || scan_add || scatter2] -> agg1 -> gemm2
//   -> agg2.
// r11-r13 lesson (3 falsified theories): the edge phase costs ~60-90us in ANY
// arrangement -- it is small-transaction bound (800K x {strided ei loads +
// device atomic + random 4B store}, ~64B fabric transactions carrying 4-8
// useful bytes; invisible in BW counters). r10's packing (coalesced ordinal
// store; random scatter hidden under gemm1) is the best measured.
// r7: gather and MFMA in separate dispatches. r8: no cross-block spin-waits.
// ---------------------------------------------------------------------------

typedef float f32x4 __attribute__((ext_vector_type(4)));
typedef __fp16 f16x8 __attribute__((ext_vector_type(8)));

static __device__ __forceinline__ float lrelu02(float x) { return x > 0.f ? x : 0.2f * x; }
static __device__ __forceinline__ float eluf(float x)    { return x > 0.f ? x : __expf(x) - 1.f; }

// --- kA: heterogeneous. blocks [0,hb): hist (+ordinal); rest: weight prep.
// edge-dtype flag per block: int64 LE with values < 2^31 has zero odd words.
__global__ __launch_bounds__(256) void kA_kernel(const int* __restrict__ ei,
                                                 int* __restrict__ deg,
                                                 int* __restrict__ ord,
                                                 const float* __restrict__ W1,
                                                 const float* __restrict__ W2,
                                                 __fp16* __restrict__ w1t,
                                                 __fp16* __restrict__ w2t,
                                                 int e, int hb) {
    __shared__ int sflag;
    int b = blockIdx.x, t = threadIdx.x;
    if (b < hb) {
        if (t < 64) {
            int m = e < 64 ? e : 64;
            int z = (t < m && ei[2 * t + 1] == 0) ? 1 : 0;
            unsigned long long bal = __ballot(z);
            if (t == 0) sflag = (__popcll(bal) >= m / 2 + 1) ? 1 : 0;
        }
        __syncthreads();
        int f = sflag;
        int i = b * 256 + t;
        if (i < e) {
            int d = f ? ei[2 * (e + i)] : ei[e + i];
            ord[i] = atomicAdd(&deg[d], 1);   // ordinal within dst row
        }
    } else {
        int j = (b - hb) * 256 + t;           // 49152 = 32768 w1t + 16384 w2t
        if (j < 32768) {
            int nn = j >> 7, k = j & 127;
            w1t[j] = (__fp16)W1[k * 256 + nn];  // [256][128]
        } else if (j < 49152) {
            int jj = j - 32768;
            int nn = jj >> 8, k = jj & 255;
            w2t[jj] = (__fp16)W2[k * 64 + nn];  // [64][256]
        }
    }
}

// --- per-block local exclusive scan (1024 elems/block) -> rloc (NOT final),
// bsum per block. Each node contributes deg[i]+1 (self-loop).
__global__ __launch_bounds__(256) void scan_blocks_kernel(const int* __restrict__ deg,
                                                          int* __restrict__ rloc,
                                                          int* __restrict__ bsum, int n) {
    __shared__ int wsum[4];
    int t = threadIdx.x, lane = t & 63, w = t >> 6;
    int base = blockIdx.x * 1024 + t * 4;
    int4 v = make_int4(0, 0, 0, 0);
    if (base + 3 < n) {
        v = *(const int4*)(deg + base);
        v.x += 1; v.y += 1; v.z += 1; v.w += 1;
    } else {
        if (base < n) v.x = deg[base] + 1;
        if (base + 1 < n) v.y = deg[base + 1] + 1;
        if (base + 2 < n) v.z = deg[base + 2] + 1;
        if (base + 3 < n) v.w = deg[base + 3] + 1;
    }
    int s = v.x + v.y + v.z + v.w;
    int incl = s;
    #pragma unroll
    for (int d = 1; d < 64; d <<= 1) { int o = __shfl_up(incl, d); if (lane >= d) incl += o; }
    if (lane == 63) wsum[w] = incl;
    __syncthreads();
    int woff = 0;
    for (int k = 0; k < w; ++k) woff += wsum[k];
    int excl = woff + incl - s;
    if (base < n) {
        int e0 = excl, e1 = e0 + v.x, e2 = e1 + v.y, e3 = e2 + v.z;
        rloc[base] = e0;
        if (base + 1 < n) rloc[base + 1] = e1;
        if (base + 2 < n) rloc[base + 2] = e2;
        if (base + 3 < n) rloc[base + 3] = e3;
    }
    if (t == 255) bsum[blockIdx.x] = woff + incl;
}

// --- kB: heterogeneous. [0,gb): gemm1; [gb,gb+sb): scan_add (rloc->rowptr);
// rest: scatter2 (ordinal-based, atomic-free, reads rloc+bsum directly).
__global__ __launch_bounds__(256) void kB_kernel(const float* __restrict__ A,
                                                 const __fp16* __restrict__ w1t,
                                                 __fp16* __restrict__ C,
                                                 const float* __restrict__ a_src,
                                                 const float* __restrict__ a_dst,
                                                 float* __restrict__ als,
                                                 float* __restrict__ ald,
                                                 const int* __restrict__ ei,
                                                 const int* __restrict__ rloc,
                                                 const int* __restrict__ bsum,
                                                 const int* __restrict__ deg,
                                                 const int* __restrict__ ord,
                                                 int* __restrict__ rowptr,
                                                 int* __restrict__ sidx,
                                                 int M, int e, int et, int n, int nb,
                                                 int gb, int sb) {
    __shared__ __fp16 sm[24064];                 // 48128 B (gemm1 section)
    int b = blockIdx.x, t = threadIdx.x;
    if (b >= gb) {
        if (b < gb + sb) {
            // ---- scan_add: finalize rowptr from rloc + bsum ----
            int i = (b - gb) * 256 + t;
            if (i < n) {
                int chunk = i >> 10;
                int off = 0;
                for (int k = 0; k < chunk; ++k) off += bsum[k];
                rowptr[i] = rloc[i] + off;
            } else if (i == n) {
                int tot = 0;
                for (int k = 0; k < nb; ++k) tot += bsum[k];
                rowptr[n] = tot;
            }
        } else {
            // ---- scatter2: sidx[rloc[d]+pref[d>>10]+ord] = src ----
            int* sflag = (int*)sm;
            int* pref  = (int*)sm + 16;          // 64 ints
            if (t < 64) {
                int m = e < 64 ? e : 64;
                int z = (t < m && ei[2 * t + 1] == 0) ? 1 : 0;
                unsigned long long bal = __ballot(z);
                if (t == 0) *sflag = (__popcll(bal) >= m / 2 + 1) ? 1 : 0;
                int v = (t < nb) ? bsum[t] : 0;
                int incl = v;
                #pragma unroll
                for (int dd = 1; dd < 64; dd <<= 1) {
                    int o = __shfl_up(incl, dd);
                    if (t >= dd) incl += o;
                }
                pref[t] = incl - v;              // exclusive prefix of bsum
            }
            __syncthreads();
            int f = *sflag;
            int i = (b - gb - sb) * 256 + t;
            if (i < et) {
                int s, d, loc;
                if (i < e) {
                    s = f ? ei[2 * i] : ei[i];
                    d = f ? ei[2 * (e + i)] : ei[e + i];
                    loc = ord[i];
                } else {
                    d = s = i - e;
                    loc = deg[d];                // self-loop -> last slot in row
                }
                sidx[rloc[d] + pref[d >> 10] + loc] = s;
            }
        }
        return;
    }
    // ---- gemm1: C[M,256] f16 = A[M,128] f32 * w1t (fp16 [256][128]); BK=64.
    // Fused layer-1 logits epilogue.
    #define AS(r, c)  sm[(r) * 72 + (c)]        // [64][72]
    #define BST(r, c) sm[4608 + (r) * 72 + (c)] // [256][72] ([n][k])
    #define CS(r, c)  sm[(r) * 264 + (c)]       // [64][264], aliases AS/BST
    float* sa = (float*)(sm + 23040);            // 256 f32
    float* sd = (float*)(sm + 23552);
    int wv = t >> 6, l = t & 63;
    int lm = l & 15, kq = l >> 4;
    int bm = b * 64;
    sa[t] = a_src[t];
    sd[t] = a_dst[t];
    f32x4 zero = {0.f, 0.f, 0.f, 0.f};
    f32x4 acc[4][4] = {{zero, zero, zero, zero}, {zero, zero, zero, zero},
                       {zero, zero, zero, zero}, {zero, zero, zero, zero}};
    int arow = t >> 2, akp = (t & 3) * 16;
    for (int k0 = 0; k0 < 128; k0 += 64) {
        {   // stage A (f32 -> f16 inline): 16 k per thread
            int gr = bm + arow;
            f16x8 av0, av1;
            if (gr < M) {
                const float* ap = A + (size_t)gr * 128 + k0 + akp;
                float4 a0 = *(const float4*)(ap + 0);
                float4 a1 = *(const float4*)(ap + 4);
                float4 a2 = *(const float4*)(ap + 8);
                float4 a3 = *(const float4*)(ap + 12);
                av0[0] = (__fp16)a0.x; av0[1] = (__fp16)a0.y; av0[2] = (__fp16)a0.z; av0[3] = (__fp16)a0.w;
                av0[4] = (__fp16)a1.x; av0[5] = (__fp16)a1.y; av0[6] = (__fp16)a1.z; av0[7] = (__fp16)a1.w;
                av1[0] = (__fp16)a2.x; av1[1] = (__fp16)a2.y; av1[2] = (__fp16)a2.z; av1[3] = (__fp16)a2.w;
                av1[4] = (__fp16)a3.x; av1[5] = (__fp16)a3.y; av1[6] = (__fp16)a3.z; av1[7] = (__fp16)a3.w;
            } else {
                f16x8 z = {0,0,0,0,0,0,0,0}; av0 = z; av1 = z;
            }
            *(f16x8*)&AS(arow, akp) = av0;
            *(f16x8*)&AS(arow, akp + 8) = av1;
        }
        {   // stage B: n = t, 64 k via 8 vector loads
            const __fp16* bp = w1t + (size_t)t * 128 + k0;
            #pragma unroll
            for (int c = 0; c < 8; ++c)
                *(f16x8*)&BST(t, c * 8) = *(const f16x8*)(bp + c * 8);
        }
        __syncthreads();
        #pragma unroll
        for (int ki = 0; ki < 2; ++ki) {
            int kc = ki * 32 + kq * 8;
            f16x8 af[4];
            #pragma unroll
            for (int mt = 0; mt < 4; ++mt) af[mt] = *(const f16x8*)&AS(mt * 16 + lm, kc);
            #pragma unroll
            for (int nt = 0; nt < 4; ++nt) {
                f16x8 bfrag = *(const f16x8*)&BST(wv * 64 + nt * 16 + lm, kc);
                #pragma unroll
                for (int mt = 0; mt < 4; ++mt)
                    acc[mt][nt] = __builtin_amdgcn_mfma_f32_16x16x32_f16(af[mt], bfrag, acc[mt][nt], 0, 0, 0);
            }
        }
        __syncthreads();
    }
    // transpose C through LDS
    #pragma unroll
    for (int mt = 0; mt < 4; ++mt)
        #pragma unroll
        for (int nt = 0; nt < 4; ++nt)
            #pragma unroll
            for (int r = 0; r < 4; ++r)
                CS(mt * 16 + kq * 4 + r, wv * 64 + nt * 16 + lm) = (__fp16)acc[mt][nt][r];
    __syncthreads();
    {
        int row = t >> 2, head = t & 3;
        int gr = bm + row;
        f16x8 c[8];
        #pragma unroll
        for (int q = 0; q < 8; ++q) c[q] = *(const f16x8*)&CS(row, head * 64 + q * 8);
        float ps = 0.f, pd = 0.f;
        #pragma unroll
        for (int q = 0; q < 8; ++q)
            #pragma unroll
            for (int j = 0; j < 8; ++j) {
                float v = (float)c[q][j];
                ps += v * sa[head * 64 + q * 8 + j];
                pd += v * sd[head * 64 + q * 8 + j];
            }
        if (gr < M) {
            f16x8* gp = (f16x8*)(C + (size_t)gr * 256 + head * 64);
            #pragma unroll
            for (int q = 0; q < 8; ++q) gp[q] = c[q];
            als[gr * 4 + head] = ps;
            ald[gr * 4 + head] = pd;
        }
    }
    #undef AS
    #undef BST
    #undef CS
}

// --- layer1 aggregation, fused softmax: one wave per node, 2 half-wave slots,
// 8x unroll -> 16 rows in flight per wave. No LDS.
__global__ __launch_bounds__(256) void agg1_kernel(const __fp16* __restrict__ h1,
                                                   const int* __restrict__ sidx,
                                                   const int* __restrict__ rowptr,
                                                   const float* __restrict__ als,
                                                   const float* __restrict__ ald,
                                                   const float* __restrict__ b1,
                                                   __fp16* __restrict__ x2, int n) {
    int t = threadIdx.x, wv = t >> 6, l = t & 63;
    int node = blockIdx.x * 4 + wv;
    if (node >= n) return;
    int le = l & 31, halfE = l >> 5;
    int head = le >> 3;
    float aldn = ald[node * 4 + head];
    int p0 = rowptr[node], p1 = rowptr[node + 1];
    float acc[8] = {0.f, 0.f, 0.f, 0.f, 0.f, 0.f, 0.f, 0.f};
    float accw = 0.f;
    auto body = [&](int p) {
        int s = sidx[p];
        float wt = __expf(lrelu02(als[s * 4 + head] + aldn));
        accw += wt;
        f16x8 r = *(const f16x8*)(h1 + (size_t)s * 256 + le * 8);
        #pragma unroll
        for (int j = 0; j < 8; ++j) acc[j] += wt * (float)r[j];
    };
    int p = p0 + halfE;
    for (; p + 14 < p1; p += 16) {
        body(p);      body(p + 2);  body(p + 4);  body(p + 6);
        body(p + 8);  body(p + 10); body(p + 12); body(p + 14);
    }
    for (; p < p1; p += 2) body(p);
    #pragma unroll
    for (int j = 0; j < 8; ++j) acc[j] += __shfl_down(acc[j], 32);
    accw += __shfl_down(accw, 32);
    if (l < 32) {
        float rd = 1.f / (accw + 1e-16f);
        f16x8 o;
        #pragma unroll
        for (int j = 0; j < 8; ++j) {
            float v = acc[j] * rd + b1[le * 8 + j];
            o[j] = (__fp16)eluf(v);
        }
        *(f16x8*)(x2 + (size_t)node * 256 + le * 8) = o;
    }
}

// --- GEMM2: C[M,64] f16 = A[M,256] f16 * W2 (w2t fp16 [64][256]); tile 64x64,
// BK=64. Fused single-head logit epilogue.
__global__ __launch_bounds__(256) void gemm2_kernel(const __fp16* __restrict__ A,
                                                    const __fp16* __restrict__ w2t,
                                                    __fp16* __restrict__ C,
                                                    const float* __restrict__ a_src,
                                                    const float* __restrict__ a_dst,
                                                    float* __restrict__ als,
                                                    float* __restrict__ ald, int M) {
    __shared__ __fp16 sm[9216];
    #define AS(r, c)  sm[(r) * 72 + (c)]
    #define BST(r, c) sm[4608 + (r) * 72 + (c)]
    #define CS(r, c)  sm[(r) * 72 + (c)]
    int t = threadIdx.x;
    int wv = t >> 6, l = t & 63;
    int lm = l & 15, kq = l >> 4;
    int bm = blockIdx.x * 64;
    f32x4 zero = {0.f, 0.f, 0.f, 0.f};
    f32x4 acc[4] = {zero, zero, zero, zero};
    int arow = t >> 2, akp = (t & 3) * 16;
    int bn = t & 63, bkc = (t >> 6) * 16;
    for (int k0 = 0; k0 < 256; k0 += 64) {
        {
            int gr = bm + arow;
            f16x8 av0, av1;
            if (gr < M) {
                const __fp16* ap = A + (size_t)gr * 256 + k0 + akp;
                av0 = *(const f16x8*)(ap);
                av1 = *(const f16x8*)(ap + 8);
            } else { f16x8 z = {0,0,0,0,0,0,0,0}; av0 = z; av1 = z; }
            *(f16x8*)&AS(arow, akp) = av0;
            *(f16x8*)&AS(arow, akp + 8) = av1;
        }
        {
            const __fp16* bp = w2t + (size_t)bn * 256 + k0 + bkc;
            *(f16x8*)&BST(bn, bkc) = *(const f16x8*)(bp);
            *(f16x8*)&BST(bn, bkc + 8) = *(const f16x8*)(bp + 8);
        }
        __syncthreads();
        #pragma unroll
        for (int ki = 0; ki < 2; ++ki) {
            int kc = ki * 32 + kq * 8;
            f16x8 bfrag = *(const f16x8*)&BST(wv * 16 + lm, kc);
            #pragma unroll
            for (int mt = 0; mt < 4; ++mt) {
                f16x8 afrag = *(const f16x8*)&AS(mt * 16 + lm, kc);
                acc[mt] = __builtin_amdgcn_mfma_f32_16x16x32_f16(afrag, bfrag, acc[mt], 0, 0, 0);
            }
        }
        __syncthreads();
    }
    #pragma unroll
    for (int mt = 0; mt < 4; ++mt)
        #pragma unroll
        for (int r = 0; r < 4; ++r)
            CS(mt * 16 + kq * 4 + r, wv * 16 + lm) = (__fp16)acc[mt][r];
    __syncthreads();
    {
        int row = t >> 2, ch = (t & 3) * 16;
        int gr = bm + row;
        f16x8 c0 = *(const f16x8*)&CS(row, ch);
        f16x8 c1 = *(const f16x8*)&CS(row, ch + 8);
        if (gr < M) {
            f16x8* gp = (f16x8*)(C + (size_t)gr * 64 + ch);
            gp[0] = c0; gp[1] = c1;
        }
        float ps = 0.f, pd = 0.f;
        #pragma unroll
        for (int j = 0; j < 8; ++j) {
            float v0 = (float)c0[j], v1 = (float)c1[j];
            ps += v0 * a_src[ch + j] + v1 * a_src[ch + 8 + j];
            pd += v0 * a_dst[ch + j] + v1 * a_dst[ch + 8 + j];
        }
        ps += __shfl_down(ps, 2); ps += __shfl_down(ps, 1);
        pd += __shfl_down(pd, 2); pd += __shfl_down(pd, 1);
        if ((t & 3) == 0 && gr < M) {
            als[gr] = ps;
            ald[gr] = pd;
        }
    }
    #undef AS
    #undef BST
    #undef CS
}

// --- layer2 aggregation, fused softmax: one wave per node; 8 slots x 8 lanes,
// 4x unroll (16 rows in flight).
__global__ __launch_bounds__(256) void agg2_kernel(const __fp16* __restrict__ h2,
                                                   const int* __restrict__ sidx,
                                                   const int* __restrict__ rowptr,
                                                   const float* __restrict__ als,
                                                   const float* __restrict__ ald,
                                                   const float* __restrict__ b2,
                                                   float* __restrict__ out, int n) {
    int t = threadIdx.x, wv = t >> 6, l = t & 63;
    int node = blockIdx.x * 4 + wv;
    if (node >= n) return;
    int slot = l >> 3, cq = l & 7;
    float aldn = ald[node];
    int p0 = rowptr[node], p1 = rowptr[node + 1];
    float acc[8] = {0.f, 0.f, 0.f, 0.f, 0.f, 0.f, 0.f, 0.f};
    float accw = 0.f;
    auto body = [&](int p) {
        int s = sidx[p];
        float wt = __expf(lrelu02(als[s] + aldn));
        accw += wt;
        f16x8 r = *(const f16x8*)(h2 + (size_t)s * 64 + cq * 8);
        #pragma unroll
        for (int j = 0; j < 8; ++j) acc[j] += wt * (float)r[j];
    };
    int p = p0 + slot;
    for (; p + 24 < p1; p += 32) { body(p); body(p + 8); body(p + 16); body(p + 24); }
    for (; p < p1; p += 8) body(p);
    #pragma unroll
    for (int j = 0; j < 8; ++j) {
        acc[j] += __shfl_down(acc[j], 32);
        acc[j] += __shfl_down(acc[j], 16);
        acc[j] += __shfl_down(acc[j], 8);
    }
    accw += __shfl_down(accw, 32);
    accw += __shfl_down(accw, 16);
    accw += __shfl_down(accw, 8);
    if (l < 8) {
        float rd = 1.f / (accw + 1e-16f);
        float4 o0, o1;
        o0.x = eluf(acc[0] * rd + b2[cq * 8 + 0]);
        o0.y = eluf(acc[1] * rd + b2[cq * 8 + 1]);
        o0.z = eluf(acc[2] * rd + b2[cq * 8 + 2]);
        o0.w = eluf(acc[3] * rd + b2[cq * 8 + 3]);
        o1.x = eluf(acc[4] * rd + b2[cq * 8 + 4]);
        o1.y = eluf(acc[5] * rd + b2[cq * 8 + 5]);
        o1.z = eluf(acc[6] * rd + b2[cq * 8 + 6]);
        o1.w = eluf(acc[7] * rd + b2[cq * 8 + 7]);
        float4* gp = (float4*)(out + (size_t)node * 64 + cq * 8);
        gp[0] = o0; gp[1] = o1;
    }
}

extern "C" void kernel_launch(void* const* d_in, const int* in_sizes, int n_in,
                              void* d_out, int out_size, void* d_ws, size_t ws_size,
                              hipStream_t stream) {
    const float* x   = (const float*)d_in[0];
    const int*   ei  = (const int*)d_in[1];
    const float* W1  = (const float*)d_in[2];
    const float* as1 = (const float*)d_in[3];
    const float* ad1 = (const float*)d_in[4];
    const float* b1  = (const float*)d_in[5];
    const float* W2  = (const float*)d_in[6];
    const float* as2 = (const float*)d_in[7];
    const float* ad2 = (const float*)d_in[8];
    const float* b2  = (const float*)d_in[9];
    float* out = (float*)d_out;

    const int n  = in_sizes[0] / 128;  // 50000
    const int e  = in_sizes[1] / 2;    // 800000
    const int et = e + n;

    char* w = (char*)d_ws;
    size_t off = 0;
    auto take = [&](size_t bytes) -> void* {
        void* p = w + off;
        off = (off + bytes + 255) & ~(size_t)255;
        return p;
    };
    __fp16* h1h = (__fp16*)take((size_t)n * 256 * 2);
    __fp16* x2h = (__fp16*)take((size_t)n * 256 * 2);
    __fp16* h2h = (__fp16*)take((size_t)n * 64 * 2);
    __fp16* w1t = (__fp16*)take((size_t)256 * 128 * 2);
    __fp16* w2t = (__fp16*)take((size_t)64 * 256 * 2);
    float* al1s = (float*)take((size_t)n * 4 * 4);
    float* al1d = (float*)take((size_t)n * 4 * 4);
    float* al2s = (float*)take((size_t)n * 4);
    float* al2d = (float*)take((size_t)n * 4);
    int* deg    = (int*)take((size_t)(n + 1) * 4);
    int* rloc   = (int*)take((size_t)(n + 1) * 4);
    int* rowptr = (int*)take((size_t)(n + 1) * 4);
    int* ord    = (int*)take((size_t)e * 4);
    int* sidx   = (int*)take((size_t)et * 4);
    int* bsum   = (int*)take(256);

    const int hb = (e + 255) / 256;          // hist blocks (3125)
    const int pb = (49152 + 255) / 256;      // prep blocks (192)
    const int nb = (n + 1023) / 1024;        // scan blocks (49)
    const int gb = (n + 63) / 64;            // gemm1 blocks (782)
    const int sb = (n + 1 + 255) / 256;      // scan_add blocks (196)
    const int cb = (et + 255) / 256;         // scatter blocks (3325)

    // 1. zero deg
    hipMemsetAsync(deg, 0, (size_t)(n + 1) * 4, stream);
    // 2. kA: hist(+ordinal) || weight prep
    kA_kernel<<<hb + pb, 256, 0, stream>>>(ei, deg, ord, W1, W2, w1t, w2t, e, hb);
    // 3. local scan -> rloc, bsum
    scan_blocks_kernel<<<nb, 256, 0, stream>>>(deg, rloc, bsum, n);
    // 4. kB: gemm1 || scan_add || scatter2 (mutually independent)
    kB_kernel<<<gb + sb + cb, 256, 0, stream>>>(x, w1t, h1h, as1, ad1, al1s, al1d,
                                                ei, rloc, bsum, deg, ord, rowptr, sidx,
                                                n, e, et, n, nb, gb, sb);
    // 5. layer-1 aggregation (softmax fused)
    agg1_kernel<<<(n + 3) / 4, 256, 0, stream>>>(h1h, sidx, rowptr, al1s, al1d, b1, x2h, n);
    // 6. layer-2 GEMM (+logits)
    gemm2_kernel<<<(n + 63) / 64, 256, 0, stream>>>(x2h, w2t, h2h, as2, ad2, al2s, al2d, n);
    // 7. layer-2 aggregation -> output
    agg2_kernel<<<(n + 3) / 4, 256, 0, stream>>>(h2h, sidx, rowptr, al2s, al2d, b2, out, n);
}

// Round 15
// 257.505 us; speedup vs baseline: 1.0689x; 1.0689x over previous
//
#include <hip/hip_runtime.h>
#include <hip/hip_bf16.h>
#include <cstdint>
#include <cstddef>

// ---------------------------------------------------------------------------
// FarmerGAT round 15: exact r10 revert (best measured: 257.8us).
//   memset(deg) -> kA [hist(saves ordinal) | prep w1t/w2t] -> scan_blocks
//   (-> rloc,bsum) -> kB [gemm1 || scan_add || scatter2] -> agg1 -> gemm2
//   -> agg2.
// r14 lesson (profile-proven): agg1 is TLP-latency-bound -- 8x unroll doubled
// VGPR (32->64), halved occupancy (67->32%), fill rate 3.67->2.88 TB/s,
// 65->83us. The 4x-unroll/VGPR-32 point is the measured optimum.
// r11-r13: edge phase is small-transaction-bound (~60us in any arrangement);
// r10's packing (coalesced ordinal store, scatter hidden under gemm1) is best.
// r7: gather and MFMA in separate dispatches. r8: no cross-block spin-waits.
// ---------------------------------------------------------------------------

typedef float f32x4 __attribute__((ext_vector_type(4)));
typedef __fp16 f16x8 __attribute__((ext_vector_type(8)));

static __device__ __forceinline__ float lrelu02(float x) { return x > 0.f ? x : 0.2f * x; }
static __device__ __forceinline__ float eluf(float x)    { return x > 0.f ? x : __expf(x) - 1.f; }

// --- kA: heterogeneous. blocks [0,hb): hist (+ordinal); rest: weight prep.
// edge-dtype flag per block: int64 LE with values < 2^31 has zero odd words.
__global__ __launch_bounds__(256) void kA_kernel(const int* __restrict__ ei,
                                                 int* __restrict__ deg,
                                                 int* __restrict__ ord,
                                                 const float* __restrict__ W1,
                                                 const float* __restrict__ W2,
                                                 __fp16* __restrict__ w1t,
                                                 __fp16* __restrict__ w2t,
                                                 int e, int hb) {
    __shared__ int sflag;
    int b = blockIdx.x, t = threadIdx.x;
    if (b < hb) {
        if (t < 64) {
            int m = e < 64 ? e : 64;
            int z = (t < m && ei[2 * t + 1] == 0) ? 1 : 0;
            unsigned long long bal = __ballot(z);
            if (t == 0) sflag = (__popcll(bal) >= m / 2 + 1) ? 1 : 0;
        }
        __syncthreads();
        int f = sflag;
        int i = b * 256 + t;
        if (i < e) {
            int d = f ? ei[2 * (e + i)] : ei[e + i];
            ord[i] = atomicAdd(&deg[d], 1);   // ordinal within dst row
        }
    } else {
        int j = (b - hb) * 256 + t;           // 49152 = 32768 w1t + 16384 w2t
        if (j < 32768) {
            int nn = j >> 7, k = j & 127;
            w1t[j] = (__fp16)W1[k * 256 + nn];  // [256][128]
        } else if (j < 49152) {
            int jj = j - 32768;
            int nn = jj >> 8, k = jj & 255;
            w2t[jj] = (__fp16)W2[k * 64 + nn];  // [64][256]
        }
    }
}

// --- per-block local exclusive scan (1024 elems/block) -> rloc (NOT final),
// bsum per block. Each node contributes deg[i]+1 (self-loop).
__global__ __launch_bounds__(256) void scan_blocks_kernel(const int* __restrict__ deg,
                                                          int* __restrict__ rloc,
                                                          int* __restrict__ bsum, int n) {
    __shared__ int wsum[4];
    int t = threadIdx.x, lane = t & 63, w = t >> 6;
    int base = blockIdx.x * 1024 + t * 4;
    int4 v = make_int4(0, 0, 0, 0);
    if (base + 3 < n) {
        v = *(const int4*)(deg + base);
        v.x += 1; v.y += 1; v.z += 1; v.w += 1;
    } else {
        if (base < n) v.x = deg[base] + 1;
        if (base + 1 < n) v.y = deg[base + 1] + 1;
        if (base + 2 < n) v.z = deg[base + 2] + 1;
        if (base + 3 < n) v.w = deg[base + 3] + 1;
    }
    int s = v.x + v.y + v.z + v.w;
    int incl = s;
    #pragma unroll
    for (int d = 1; d < 64; d <<= 1) { int o = __shfl_up(incl, d); if (lane >= d) incl += o; }
    if (lane == 63) wsum[w] = incl;
    __syncthreads();
    int woff = 0;
    for (int k = 0; k < w; ++k) woff += wsum[k];
    int excl = woff + incl - s;
    if (base < n) {
        int e0 = excl, e1 = e0 + v.x, e2 = e1 + v.y, e3 = e2 + v.z;
        rloc[base] = e0;
        if (base + 1 < n) rloc[base + 1] = e1;
        if (base + 2 < n) rloc[base + 2] = e2;
        if (base + 3 < n) rloc[base + 3] = e3;
    }
    if (t == 255) bsum[blockIdx.x] = woff + incl;
}

// --- kB: heterogeneous. [0,gb): gemm1; [gb,gb+sb): scan_add (rloc->rowptr);
// rest: scatter2 (ordinal-based, atomic-free, reads rloc+bsum directly).
__global__ __launch_bounds__(256) void kB_kernel(const float* __restrict__ A,
                                                 const __fp16* __restrict__ w1t,
                                                 __fp16* __restrict__ C,
                                                 const float* __restrict__ a_src,
                                                 const float* __restrict__ a_dst,
                                                 float* __restrict__ als,
                                                 float* __restrict__ ald,
                                                 const int* __restrict__ ei,
                                                 const int* __restrict__ rloc,
                                                 const int* __restrict__ bsum,
                                                 const int* __restrict__ deg,
                                                 const int* __restrict__ ord,
                                                 int* __restrict__ rowptr,
                                                 int* __restrict__ sidx,
                                                 int M, int e, int et, int n, int nb,
                                                 int gb, int sb) {
    __shared__ __fp16 sm[24064];                 // 48128 B (gemm1 section)
    int b = blockIdx.x, t = threadIdx.x;
    if (b >= gb) {
        if (b < gb + sb) {
            // ---- scan_add: finalize rowptr from rloc + bsum ----
            int i = (b - gb) * 256 + t;
            if (i < n) {
                int chunk = i >> 10;
                int off = 0;
                for (int k = 0; k < chunk; ++k) off += bsum[k];
                rowptr[i] = rloc[i] + off;
            } else if (i == n) {
                int tot = 0;
                for (int k = 0; k < nb; ++k) tot += bsum[k];
                rowptr[n] = tot;
            }
        } else {
            // ---- scatter2: sidx[rloc[d]+pref[d>>10]+ord] = src ----
            int* sflag = (int*)sm;
            int* pref  = (int*)sm + 16;          // 64 ints
            if (t < 64) {
                int m = e < 64 ? e : 64;
                int z = (t < m && ei[2 * t + 1] == 0) ? 1 : 0;
                unsigned long long bal = __ballot(z);
                if (t == 0) *sflag = (__popcll(bal) >= m / 2 + 1) ? 1 : 0;
                int v = (t < nb) ? bsum[t] : 0;
                int incl = v;
                #pragma unroll
                for (int dd = 1; dd < 64; dd <<= 1) {
                    int o = __shfl_up(incl, dd);
                    if (t >= dd) incl += o;
                }
                pref[t] = incl - v;              // exclusive prefix of bsum
            }
            __syncthreads();
            int f = *sflag;
            int i = (b - gb - sb) * 256 + t;
            if (i < et) {
                int s, d, loc;
                if (i < e) {
                    s = f ? ei[2 * i] : ei[i];
                    d = f ? ei[2 * (e + i)] : ei[e + i];
                    loc = ord[i];
                } else {
                    d = s = i - e;
                    loc = deg[d];                // self-loop -> last slot in row
                }
                sidx[rloc[d] + pref[d >> 10] + loc] = s;
            }
        }
        return;
    }
    // ---- gemm1: C[M,256] f16 = A[M,128] f32 * w1t (fp16 [256][128]); BK=64.
    // Fused layer-1 logits epilogue.
    #define AS(r, c)  sm[(r) * 72 + (c)]        // [64][72]
    #define BST(r, c) sm[4608 + (r) * 72 + (c)] // [256][72] ([n][k])
    #define CS(r, c)  sm[(r) * 264 + (c)]       // [64][264], aliases AS/BST
    float* sa = (float*)(sm + 23040);            // 256 f32
    float* sd = (float*)(sm + 23552);
    int wv = t >> 6, l = t & 63;
    int lm = l & 15, kq = l >> 4;
    int bm = b * 64;
    sa[t] = a_src[t];
    sd[t] = a_dst[t];
    f32x4 zero = {0.f, 0.f, 0.f, 0.f};
    f32x4 acc[4][4] = {{zero, zero, zero, zero}, {zero, zero, zero, zero},
                       {zero, zero, zero, zero}, {zero, zero, zero, zero}};
    int arow = t >> 2, akp = (t & 3) * 16;
    for (int k0 = 0; k0 < 128; k0 += 64) {
        {   // stage A (f32 -> f16 inline): 16 k per thread
            int gr = bm + arow;
            f16x8 av0, av1;
            if (gr < M) {
                const float* ap = A + (size_t)gr * 128 + k0 + akp;
                float4 a0 = *(const float4*)(ap + 0);
                float4 a1 = *(const float4*)(ap + 4);
                float4 a2 = *(const float4*)(ap + 8);
                float4 a3 = *(const float4*)(ap + 12);
                av0[0] = (__fp16)a0.x; av0[1] = (__fp16)a0.y; av0[2] = (__fp16)a0.z; av0[3] = (__fp16)a0.w;
                av0[4] = (__fp16)a1.x; av0[5] = (__fp16)a1.y; av0[6] = (__fp16)a1.z; av0[7] = (__fp16)a1.w;
                av1[0] = (__fp16)a2.x; av1[1] = (__fp16)a2.y; av1[2] = (__fp16)a2.z; av1[3] = (__fp16)a2.w;
                av1[4] = (__fp16)a3.x; av1[5] = (__fp16)a3.y; av1[6] = (__fp16)a3.z; av1[7] = (__fp16)a3.w;
            } else {
                f16x8 z = {0,0,0,0,0,0,0,0}; av0 = z; av1 = z;
            }
            *(f16x8*)&AS(arow, akp) = av0;
            *(f16x8*)&AS(arow, akp + 8) = av1;
        }
        {   // stage B: n = t, 64 k via 8 vector loads
            const __fp16* bp = w1t + (size_t)t * 128 + k0;
            #pragma unroll
            for (int c = 0; c < 8; ++c)
                *(f16x8*)&BST(t, c * 8) = *(const f16x8*)(bp + c * 8);
        }
        __syncthreads();
        #pragma unroll
        for (int ki = 0; ki < 2; ++ki) {
            int kc = ki * 32 + kq * 8;
            f16x8 af[4];
            #pragma unroll
            for (int mt = 0; mt < 4; ++mt) af[mt] = *(const f16x8*)&AS(mt * 16 + lm, kc);
            #pragma unroll
            for (int nt = 0; nt < 4; ++nt) {
                f16x8 bfrag = *(const f16x8*)&BST(wv * 64 + nt * 16 + lm, kc);
                #pragma unroll
                for (int mt = 0; mt < 4; ++mt)
                    acc[mt][nt] = __builtin_amdgcn_mfma_f32_16x16x32_f16(af[mt], bfrag, acc[mt][nt], 0, 0, 0);
            }
        }
        __syncthreads();
    }
    // transpose C through LDS
    #pragma unroll
    for (int mt = 0; mt < 4; ++mt)
        #pragma unroll
        for (int nt = 0; nt < 4; ++nt)
            #pragma unroll
            for (int r = 0; r < 4; ++r)
                CS(mt * 16 + kq * 4 + r, wv * 64 + nt * 16 + lm) = (__fp16)acc[mt][nt][r];
    __syncthreads();
    {
        int row = t >> 2, head = t & 3;
        int gr = bm + row;
        f16x8 c[8];
        #pragma unroll
        for (int q = 0; q < 8; ++q) c[q] = *(const f16x8*)&CS(row, head * 64 + q * 8);
        float ps = 0.f, pd = 0.f;
        #pragma unroll
        for (int q = 0; q < 8; ++q)
            #pragma unroll
            for (int j = 0; j < 8; ++j) {
                float v = (float)c[q][j];
                ps += v * sa[head * 64 + q * 8 + j];
                pd += v * sd[head * 64 + q * 8 + j];
            }
        if (gr < M) {
            f16x8* gp = (f16x8*)(C + (size_t)gr * 256 + head * 64);
            #pragma unroll
            for (int q = 0; q < 8; ++q) gp[q] = c[q];
            als[gr * 4 + head] = ps;
            ald[gr * 4 + head] = pd;
        }
    }
    #undef AS
    #undef BST
    #undef CS
}

// --- layer1 aggregation, fused softmax: one wave per node, 2 half-wave slots,
// 4x unroll -> 8 rows in flight per wave. No LDS. (VGPR 32 / occupancy ~67% --
// the measured optimum; 8x unroll regressed via occupancy, r14.)
__global__ __launch_bounds__(256) void agg1_kernel(const __fp16* __restrict__ h1,
                                                   const int* __restrict__ sidx,
                                                   const int* __restrict__ rowptr,
                                                   const float* __restrict__ als,
                                                   const float* __restrict__ ald,
                                                   const float* __restrict__ b1,
                                                   __fp16* __restrict__ x2, int n) {
    int t = threadIdx.x, wv = t >> 6, l = t & 63;
    int node = blockIdx.x * 4 + wv;
    if (node >= n) return;
    int le = l & 31, halfE = l >> 5;
    int head = le >> 3;
    float aldn = ald[node * 4 + head];
    int p0 = rowptr[node], p1 = rowptr[node + 1];
    float acc[8] = {0.f, 0.f, 0.f, 0.f, 0.f, 0.f, 0.f, 0.f};
    float accw = 0.f;
    auto body = [&](int p) {
        int s = sidx[p];
        float wt = __expf(lrelu02(als[s * 4 + head] + aldn));
        accw += wt;
        f16x8 r = *(const f16x8*)(h1 + (size_t)s * 256 + le * 8);
        #pragma unroll
        for (int j = 0; j < 8; ++j) acc[j] += wt * (float)r[j];
    };
    int p = p0 + halfE;
    for (; p + 6 < p1; p += 8) { body(p); body(p + 2); body(p + 4); body(p + 6); }
    for (; p < p1; p += 2) body(p);
    #pragma unroll
    for (int j = 0; j < 8; ++j) acc[j] += __shfl_down(acc[j], 32);
    accw += __shfl_down(accw, 32);
    if (l < 32) {
        float rd = 1.f / (accw + 1e-16f);
        f16x8 o;
        #pragma unroll
        for (int j = 0; j < 8; ++j) {
            float v = acc[j] * rd + b1[le * 8 + j];
            o[j] = (__fp16)eluf(v);
        }
        *(f16x8*)(x2 + (size_t)node * 256 + le * 8) = o;
    }
}

// --- GEMM2: C[M,64] f16 = A[M,256] f16 * W2 (w2t fp16 [64][256]); tile 64x64,
// BK=64. Fused single-head logit epilogue.
__global__ __launch_bounds__(256) void gemm2_kernel(const __fp16* __restrict__ A,
                                                    const __fp16* __restrict__ w2t,
                                                    __fp16* __restrict__ C,
                                                    const float* __restrict__ a_src,
                                                    const float* __restrict__ a_dst,
                                                    float* __restrict__ als,
                                                    float* __restrict__ ald, int M) {
    __shared__ __fp16 sm[9216];
    #define AS(r, c)  sm[(r) * 72 + (c)]
    #define BST(r, c) sm[4608 + (r) * 72 + (c)]
    #define CS(r, c)  sm[(r) * 72 + (c)]
    int t = threadIdx.x;
    int wv = t >> 6, l = t & 63;
    int lm = l & 15, kq = l >> 4;
    int bm = blockIdx.x * 64;
    f32x4 zero = {0.f, 0.f, 0.f, 0.f};
    f32x4 acc[4] = {zero, zero, zero, zero};
    int arow = t >> 2, akp = (t & 3) * 16;
    int bn = t & 63, bkc = (t >> 6) * 16;
    for (int k0 = 0; k0 < 256; k0 += 64) {
        {
            int gr = bm + arow;
            f16x8 av0, av1;
            if (gr < M) {
                const __fp16* ap = A + (size_t)gr * 256 + k0 + akp;
                av0 = *(const f16x8*)(ap);
                av1 = *(const f16x8*)(ap + 8);
            } else { f16x8 z = {0,0,0,0,0,0,0,0}; av0 = z; av1 = z; }
            *(f16x8*)&AS(arow, akp) = av0;
            *(f16x8*)&AS(arow, akp + 8) = av1;
        }
        {
            const __fp16* bp = w2t + (size_t)bn * 256 + k0 + bkc;
            *(f16x8*)&BST(bn, bkc) = *(const f16x8*)(bp);
            *(f16x8*)&BST(bn, bkc + 8) = *(const f16x8*)(bp + 8);
        }
        __syncthreads();
        #pragma unroll
        for (int ki = 0; ki < 2; ++ki) {
            int kc = ki * 32 + kq * 8;
            f16x8 bfrag = *(const f16x8*)&BST(wv * 16 + lm, kc);
            #pragma unroll
            for (int mt = 0; mt < 4; ++mt) {
                f16x8 afrag = *(const f16x8*)&AS(mt * 16 + lm, kc);
                acc[mt] = __builtin_amdgcn_mfma_f32_16x16x32_f16(afrag, bfrag, acc[mt], 0, 0, 0);
            }
        }
        __syncthreads();
    }
    #pragma unroll
    for (int mt = 0; mt < 4; ++mt)
        #pragma unroll
        for (int r = 0; r < 4; ++r)
            CS(mt * 16 + kq * 4 + r, wv * 16 + lm) = (__fp16)acc[mt][r];
    __syncthreads();
    {
        int row = t >> 2, ch = (t & 3) * 16;
        int gr = bm + row;
        f16x8 c0 = *(const f16x8*)&CS(row, ch);
        f16x8 c1 = *(const f16x8*)&CS(row, ch + 8);
        if (gr < M) {
            f16x8* gp = (f16x8*)(C + (size_t)gr * 64 + ch);
            gp[0] = c0; gp[1] = c1;
        }
        float ps = 0.f, pd = 0.f;
        #pragma unroll
        for (int j = 0; j < 8; ++j) {
            float v0 = (float)c0[j], v1 = (float)c1[j];
            ps += v0 * a_src[ch + j] + v1 * a_src[ch + 8 + j];
            pd += v0 * a_dst[ch + j] + v1 * a_dst[ch + 8 + j];
        }
        ps += __shfl_down(ps, 2); ps += __shfl_down(ps, 1);
        pd += __shfl_down(pd, 2); pd += __shfl_down(pd, 1);
        if ((t & 3) == 0 && gr < M) {
            als[gr] = ps;
            ald[gr] = pd;
        }
    }
    #undef AS
    #undef BST
    #undef CS
}

// --- layer2 aggregation, fused softmax: one wave per node; 8 slots x 8 lanes,
// 4x unroll (16 rows in flight).
__global__ __launch_bounds__(256) void agg2_kernel(const __fp16* __restrict__ h2,
                                                   const int* __restrict__ sidx,
                                                   const int* __restrict__ rowptr,
                                                   const float* __restrict__ als,
                                                   const float* __restrict__ ald,
                                                   const float* __restrict__ b2,
                                                   float* __restrict__ out, int n) {
    int t = threadIdx.x, wv = t >> 6, l = t & 63;
    int node = blockIdx.x * 4 + wv;
    if (node >= n) return;
    int slot = l >> 3, cq = l & 7;
    float aldn = ald[node];
    int p0 = rowptr[node], p1 = rowptr[node + 1];
    float acc[8] = {0.f, 0.f, 0.f, 0.f, 0.f, 0.f, 0.f, 0.f};
    float accw = 0.f;
    auto body = [&](int p) {
        int s = sidx[p];
        float wt = __expf(lrelu02(als[s] + aldn));
        accw += wt;
        f16x8 r = *(const f16x8*)(h2 + (size_t)s * 64 + cq * 8);
        #pragma unroll
        for (int j = 0; j < 8; ++j) acc[j] += wt * (float)r[j];
    };
    int p = p0 + slot;
    for (; p + 24 < p1; p += 32) { body(p); body(p + 8); body(p + 16); body(p + 24); }
    for (; p < p1; p += 8) body(p);
    #pragma unroll
    for (int j = 0; j < 8; ++j) {
        acc[j] += __shfl_down(acc[j], 32);
        acc[j] += __shfl_down(acc[j], 16);
        acc[j] += __shfl_down(acc[j], 8);
    }
    accw += __shfl_down(accw, 32);
    accw += __shfl_down(accw, 16);
    accw += __shfl_down(accw, 8);
    if (l < 8) {
        float rd = 1.f / (accw + 1e-16f);
        float4 o0, o1;
        o0.x = eluf(acc[0] * rd + b2[cq * 8 + 0]);
        o0.y = eluf(acc[1] * rd + b2[cq * 8 + 1]);
        o0.z = eluf(acc[2] * rd + b2[cq * 8 + 2]);
        o0.w = eluf(acc[3] * rd + b2[cq * 8 + 3]);
        o1.x = eluf(acc[4] * rd + b2[cq * 8 + 4]);
        o1.y = eluf(acc[5] * rd + b2[cq * 8 + 5]);
        o1.z = eluf(acc[6] * rd + b2[cq * 8 + 6]);
        o1.w = eluf(acc[7] * rd + b2[cq * 8 + 7]);
        float4* gp = (float4*)(out + (size_t)node * 64 + cq * 8);
        gp[0] = o0; gp[1] = o1;
    }
}

extern "C" void kernel_launch(void* const* d_in, const int* in_sizes, int n_in,
                              void* d_out, int out_size, void* d_ws, size_t ws_size,
                              hipStream_t stream) {
    const float* x   = (const float*)d_in[0];
    const int*   ei  = (const int*)d_in[1];
    const float* W1  = (const float*)d_in[2];
    const float* as1 = (const float*)d_in[3];
    const float* ad1 = (const float*)d_in[4];
    const float* b1  = (const float*)d_in[5];
    const float* W2  = (const float*)d_in[6];
    const float* as2 = (const float*)d_in[7];
    const float* ad2 = (const float*)d_in[8];
    const float* b2  = (const float*)d_in[9];
    float* out = (float*)d_out;

    const int n  = in_sizes[0] / 128;  // 50000
    const int e  = in_sizes[1] / 2;    // 800000
    const int et = e + n;

    char* w = (char*)d_ws;
    size_t off = 0;
    auto take = [&](size_t bytes) -> void* {
        void* p = w + off;
        off = (off + bytes + 255) & ~(size_t)255;
        return p;
    };
    __fp16* h1h = (__fp16*)take((size_t)n * 256 * 2);
    __fp16* x2h = (__fp16*)take((size_t)n * 256 * 2);
    __fp16* h2h = (__fp16*)take((size_t)n * 64 * 2);
    __fp16* w1t = (__fp16*)take((size_t)256 * 128 * 2);
    __fp16* w2t = (__fp16*)take((size_t)64 * 256 * 2);
    float* al1s = (float*)take((size_t)n * 4 * 4);
    float* al1d = (float*)take((size_t)n * 4 * 4);
    float* al2s = (float*)take((size_t)n * 4);
    float* al2d = (float*)take((size_t)n * 4);
    int* deg    = (int*)take((size_t)(n + 1) * 4);
    int* rloc   = (int*)take((size_t)(n + 1) * 4);
    int* rowptr = (int*)take((size_t)(n + 1) * 4);
    int* ord    = (int*)take((size_t)e * 4);
    int* sidx   = (int*)take((size_t)et * 4);
    int* bsum   = (int*)take(256);

    const int hb = (e + 255) / 256;          // hist blocks (3125)
    const int pb = (49152 + 255) / 256;      // prep blocks (192)
    const int nb = (n + 1023) / 1024;        // scan blocks (49)
    const int gb = (n + 63) / 64;            // gemm1 blocks (782)
    const int sb = (n + 1 + 255) / 256;      // scan_add blocks (196)
    const int cb = (et + 255) / 256;         // scatter blocks (3325)

    // 1. zero deg
    hipMemsetAsync(deg, 0, (size_t)(n + 1) * 4, stream);
    // 2. kA: hist(+ordinal) || weight prep
    kA_kernel<<<hb + pb, 256, 0, stream>>>(ei, deg, ord, W1, W2, w1t, w2t, e, hb);
    // 3. local scan -> rloc, bsum
    scan_blocks_kernel<<<nb, 256, 0, stream>>>(deg, rloc, bsum, n);
    // 4. kB: gemm1 || scan_add || scatter2 (mutually independent)
    kB_kernel<<<gb + sb + cb, 256, 0, stream>>>(x, w1t, h1h, as1, ad1, al1s, al1d,
                                                ei, rloc, bsum, deg, ord, rowptr, sidx,
                                                n, e, et, n, nb, gb, sb);
    // 5. layer-1 aggregation (softmax fused)
    agg1_kernel<<<(n + 3) / 4, 256, 0, stream>>>(h1h, sidx, rowptr, al1s, al1d, b1, x2h, n);
    // 6. layer-2 GEMM (+logits)
    gemm2_kernel<<<(n + 63) / 64, 256, 0, stream>>>(x2h, w2t, h2h, as2, ad2, al2s, al2d, n);
    // 7. layer-2 aggregation -> output
    agg2_kernel<<<(n + 3) / 4, 256, 0, stream>>>(h2h, sidx, rowptr, al2s, al2d, b2, out, n);
}